// Round 11
// baseline (2894.158 us; speedup 1.0000x reference)
//
#include <hip/hip_runtime.h>

// Sizes
#define B_   32
#define S_   64
#define T_   64
#define H_   1024
#define H2_  2048
#define E_   512
#define V_   32000
#define K3_  3072
#define BT_  2048

typedef unsigned short u16;
typedef __attribute__((ext_vector_type(8))) short short8_t;  // 8 x bf16
typedef __attribute__((ext_vector_type(4))) float f32x4;

__device__ __forceinline__ u16 f2bf(float f) {
  unsigned x = __float_as_uint(f);
  unsigned r = (x + 0x7fffu + ((x >> 16) & 1u)) >> 16;  // RNE
  return (u16)r;
}
__device__ __forceinline__ float bf2f(u16 h) {
  return __uint_as_float(((unsigned)h) << 16);
}
__device__ __forceinline__ float frcp(float x) { return __builtin_amdgcn_rcpf(x); }
__device__ __forceinline__ float ftanh(float x) {
  float e = __expf(2.f * x);
  return 1.f - 2.f * frcp(e + 1.f);
}
__device__ __forceinline__ float fsigm(float x) {
  return frcp(1.f + __expf(-x));
}

#define KEEPV(x) asm volatile("" : "+v"(x))

__device__ __forceinline__ void st_u16(u16* p, u16 v) {
  __hip_atomic_store(p, v, __ATOMIC_RELAXED, __HIP_MEMORY_SCOPE_AGENT);
}
__device__ __forceinline__ void st_f32(float* p, float v) {
  __hip_atomic_store(p, v, __ATOMIC_RELAXED, __HIP_MEMORY_SCOPE_AGENT);
}

// ---------------- workspace layout (bytes) ----------------
#define MB_ (1ull << 20)
#define KB_ (1ull << 10)
#define X_OFF    (0)               // 4MB x (pre-loop) / spp versions (loop)
#define SPP_OFF  (0)               // 64 versions x 64KB
#define XGR_OFF  (4*MB_)           // 8MB (persistent through loop)
#define XG2_OFF  (12*MB_)          // 8MB
#define ENCT_OFF (20*MB_)          // 8MB pre-loop (pinned) — aliased by Xc in loop
#define XCV_OFF  (20*MB_)          // Xc versions t=0..63 x 256KB -> [20,36)
#define ENCP_OFF (28*MB_)          // 4MB pre-loop (pinned)
#define W2_OFF   (36*MB_)          // 2MB Wprev slices (persistent)
#define WGF_OFF  (38*MB_)          // 24MB pre-loop -> [38,62); aliased by Xs/dech
#define XSV_OFF  (38*MB_)          // Xs versions t=1..64 x 128KB -> [38,46)
#define DECH_OFF (46*MB_)          // 4MB (persistent until gemm2)
#define XS0_OFF  (62*MB_)          // 128KB
#define MB_OFF   (62*MB_ + 128*KB_)  // 128KB mini-bar counters
#define BAR_OFF  (62*MB_ + 256*KB_)  // 8KB
#define WLB_OFF  (62*MB_ + 272*KB_)  // 2KB
#define BCR_OFF  (62*MB_ + 276*KB_)  // 4KB
#define BC2_OFF  (62*MB_ + 280*KB_)  // 4KB

__device__ __forceinline__ u16* xs_hi(char* w, int t) {
  return (u16*)(t == 0 ? (w + XS0_OFF) : (w + XSV_OFF + (size_t)(t - 1) * 131072));
}
__device__ __forceinline__ u16* xc_hi(char* w, int t) {
  return (u16*)(w + XCV_OFF + (size_t)t * 262144);
}
__device__ __forceinline__ float* spp_v(char* w, int t) {
  return (float*)(w + SPP_OFF + (size_t)t * 65536);
}

// ---------------- shared GEMM body (prologue) ----------------
__device__ void gemm_body(char* smemRaw,
                          const float* __restrict__ A, int lda,
                          const float* __restrict__ Bm, int ldb,
                          void* __restrict__ Cv, int ldc, int outBf16,
                          const float* __restrict__ bias, const float* __restrict__ bias2,
                          int mtiles, int ntiles, int K, int bid) {
  u16 (*As)[72] = (u16(*)[72])smemRaw;
  u16 (*Bs)[72] = (u16(*)[72])(smemRaw + 128 * 72 * 2);
  int nwg = mtiles * ntiles;
  int cpx = nwg >> 3;
  int lb = (bid & 7) * cpx + (bid >> 3);
  int ntb = lb / mtiles, mtb = lb - ntb * mtiles;
  size_t m0 = (size_t)mtb * 128, n0 = (size_t)ntb * 128;
  int t = threadIdx.x, lane = t & 63, wid = t >> 6;
  int wr = (wid >> 1) * 64, wc = (wid & 1) * 64;
  f32x4 acc[4][4] = {};
  for (int k0 = 0; k0 < K; k0 += 64) {
    #pragma unroll
    for (int i = 0; i < 8; ++i) {
      int f4 = i * 256 + t;
      int row = f4 >> 4, c4 = (f4 & 15) << 2;
      float4 v = *(const float4*)(A + (m0 + row) * (size_t)lda + k0 + c4);
      ushort4 u; u.x = f2bf(v.x); u.y = f2bf(v.y); u.z = f2bf(v.z); u.w = f2bf(v.w);
      *(ushort4*)&As[row][c4] = u;
    }
    #pragma unroll
    for (int i = 0; i < 8; ++i) {
      int f4 = i * 256 + t;
      int kr = f4 >> 5, c4 = (f4 & 31) << 2;
      float4 v = *(const float4*)(Bm + (size_t)(k0 + kr) * ldb + n0 + c4);
      Bs[c4 + 0][kr] = f2bf(v.x);
      Bs[c4 + 1][kr] = f2bf(v.y);
      Bs[c4 + 2][kr] = f2bf(v.z);
      Bs[c4 + 3][kr] = f2bf(v.w);
    }
    __syncthreads();
    #pragma unroll
    for (int kk = 0; kk < 64; kk += 32) {
      int ko = kk + (lane >> 4) * 8;
      short8_t am[4], bn[4];
      #pragma unroll
      for (int m = 0; m < 4; ++m) am[m] = *(const short8_t*)&As[wr + m * 16 + (lane & 15)][ko];
      #pragma unroll
      for (int n = 0; n < 4; ++n) bn[n] = *(const short8_t*)&Bs[wc + n * 16 + (lane & 15)][ko];
      #pragma unroll
      for (int m = 0; m < 4; ++m)
        #pragma unroll
        for (int n = 0; n < 4; ++n)
          acc[m][n] = __builtin_amdgcn_mfma_f32_16x16x32_bf16(am[m], bn[n], acc[m][n], 0, 0, 0);
    }
    __syncthreads();
  }
  #pragma unroll
  for (int n = 0; n < 4; ++n) {
    int col = wc + n * 16 + (lane & 15);
    float bv = bias ? bias[n0 + col] : 0.f;
    if (bias2) bv += bias2[n0 + col];
    #pragma unroll
    for (int m = 0; m < 4; ++m) {
      size_t row = m0 + wr + m * 16 + ((lane >> 4) << 2);
      #pragma unroll
      for (int r = 0; r < 4; ++r) {
        float val = acc[m][n][r] + bv;
        if (outBf16) ((u16*)Cv)[(row + r) * (size_t)ldc + n0 + col] = f2bf(val);
        else ((float*)Cv)[(row + r) * (size_t)ldc + n0 + col] = val;
      }
    }
  }
}

// ---------------- merged prologue ----------------
__global__ __launch_bounds__(256) void k_prep(
    float* __restrict__ x, const float* __restrict__ embed, const int* __restrict__ tgt,
    u16* __restrict__ encT, const float* __restrict__ enc_h,
    u16* __restrict__ w2, const float* __restrict__ Wprev,
    u16* __restrict__ wgf, const float* __restrict__ Wh, const float* __restrict__ Wc,
    const float* __restrict__ Wh2, const float* __restrict__ Wc2,
    u16* __restrict__ encp, const float* __restrict__ Wenc,
    const float* __restrict__ benc, const float* __restrict__ bprev,
    float* __restrict__ bcr, float* __restrict__ bc2o, u16* __restrict__ wlb,
    const float* __restrict__ bi, const float* __restrict__ bh, const float* __restrict__ bc,
    const float* __restrict__ bi2, const float* __restrict__ bh2, const float* __restrict__ bc2i,
    const float* __restrict__ wlin) {
  __shared__ char pbuf[36864];
  const int bid = blockIdx.x, t = threadIdx.x;

  if (bid < 1024) {
    int f4id = bid * 256 + t;
    int row = f4id >> 7, c4 = f4id & 127;
    int tt = row >> 5, bbb = row & 31;
    int trow = tgt[bbb * T_ + tt];
    ((float4*)x)[(size_t)row * 128 + c4] = ((const float4*)embed)[(size_t)trow * 128 + c4];
  } else if (bid < 2048) {
    u16 (*ld)[68] = (u16(*)[68])pbuf;
    int teb = bid - 1024;
    int b = teb >> 5, et = teb & 31;
    int e0 = et * 64;
    #pragma unroll
    for (int i = 0; i < 4; ++i) {
      int f4 = i * 256 + t;
      int si = f4 >> 4, e4 = (f4 & 15) << 2;
      float4 v = *(const float4*)(enc_h + ((size_t)(b * 64 + si)) * H2_ + e0 + e4);
      ld[si][e4 + 0] = f2bf(v.x); ld[si][e4 + 1] = f2bf(v.y);
      ld[si][e4 + 2] = f2bf(v.z); ld[si][e4 + 3] = f2bf(v.w);
    }
    __syncthreads();
    #pragma unroll
    for (int i = 0; i < 2; ++i) {
      int idx = i * 256 + t;
      int e = idx >> 3, s8 = (idx & 7) << 3;
      short8_t o;
      #pragma unroll
      for (int k = 0; k < 8; ++k) o[k] = (short)ld[s8 + k][e];
      *(short8_t*)(encT + ((size_t)(e0 + e)) * 2048 + b * 64 + s8) = o;
    }
  } else if (bid < 2560) {
    float (*ld)[33] = (float(*)[33])pbuf;
    int pb = bid - 2048;
    int kt = pb >> 5, jt = pb & 31;
    int k0 = kt * 64, j0 = jt * 32;
    #pragma unroll
    for (int i = 0; i < 8; ++i) {
      int idx = i * 256 + t; int kr = idx >> 5, jc = idx & 31;
      ld[kr][jc] = Wprev[(size_t)(k0 + kr) * H_ + j0 + jc];
    }
    __syncthreads();
    int jloc = t >> 3, kk8 = t & 7;
    int j = j0 + jloc;
    int eg = j >> 7;
    int th = ((j & 127) << 2) | (kt >> 2);
    int i = ((kt & 3) << 3) | kk8;
    short8_t o;
    #pragma unroll
    for (int e = 0; e < 8; ++e) o[e] = (short)f2bf(ld[kk8 * 8 + e][jloc]);
    *(short8_t*)(w2 + ((size_t)((eg * 512 + th) * 32 + i)) * 8) = o;
  } else if (bid < 5632) {
    float (*ld)[33] = (float(*)[33])pbuf;
    int pgb = bid - 2560;
    int sel = pgb & 1;
    int jt  = (pgb >> 1) & 31;
    int kt  = pgb >> 6;
    int k0 = kt * 64, j0 = jt * 32;
    const float* srcW = (k0 < H_) ? (sel ? Wh2 : Wh) : (sel ? Wc2 : Wc);
    int ldw = sel ? H_ : H2_;
    int koff = (k0 < H_) ? k0 : (k0 - H_);
    #pragma unroll
    for (int i = 0; i < 8; ++i) {
      int idx = i * 256 + t; int kr = idx >> 5, jc = idx & 31;
      ld[kr][jc] = srcW[(size_t)(koff + kr) * ldw + j0 + jc];
    }
    __syncthreads();
    #pragma unroll
    for (int it = 0; it < 2; ++it) {
      int u = it * 256 + t;
      int m = u & 3, sub = (u >> 2) & 3, kbl = (u >> 4) & 1, islo = (u >> 5) & 1, gg = u >> 6;
      int jjLoc = gg * 4 + m;
      int p = 2 * (j0 + jjLoc) + sel;
      int g = p >> 3, cc = p & 7;
      int c = cc + 8 * islo;
      int KB = kt * 2 + kbl;
      size_t lin = ((size_t)(g * 96 + KB) * 4 + sub) * 16 + c;
      short8_t o;
      #pragma unroll
      for (int j = 0; j < 8; ++j) {
        float v = ld[kbl * 32 + sub * 8 + j][jjLoc];
        u16 h = f2bf(v);
        o[j] = (short)(islo ? f2bf(v - bf2f(h)) : h);
      }
      *(short8_t*)(wgf + lin * 8) = o;
    }
  } else if (bid < 5760) {
    gemm_body(pbuf, enc_h, H2_, Wenc, H_, encp, H_, 1, benc, bprev, 16, 8, H2_, bid - 5632);
  } else {
    int j = (bid - 5760) * 256 + t;
    if (j < H_) {
      bcr[j]  = bi[j]  + bh[j]  + bc[j];
      bc2o[j] = bi2[j] + bh2[j] + bc2i[j];
      wlb[j]  = f2bf(wlin[j]);
    }
  }
}

__global__ __launch_bounds__(256) void k_gemm12(
    const float* __restrict__ x,
    const float* __restrict__ Wi, const float* __restrict__ Wi2,
    float* __restrict__ xgr, float* __restrict__ xg2,
    const float* __restrict__ bcr, const float* __restrict__ bc2) {
  __shared__ char pbuf[36864];
  if (blockIdx.x < 128)
    gemm_body(pbuf, x, E_, Wi, H2_, xgr, H_, 0, bcr, nullptr, 16, 8, E_, blockIdx.x);
  else
    gemm_body(pbuf, x, E_, Wi2, H_, xg2, H_, 0, bc2, nullptr, 16, 8, E_, blockIdx.x - 128);
}

// fused vocab projection: dech bf16 [2048][1024] @ out_W fp32 [1024][32000]
// B transposed in-kernel via padded LDS stage (no wot buffer, no wtrans pass).
__global__ __launch_bounds__(256) void k_gemm2d(
    const u16* __restrict__ A, const float* __restrict__ W,
    float* __restrict__ C, const float* __restrict__ bias) {
  __shared__ u16 As[128][72];       // 18.4 KB
  __shared__ u16 Bs[128][72];       // 18.4 KB  [n][k]
  __shared__ u16 Bstage[64 * 132];  // 16.9 KB  [k][n] padded (+4)
  int bid = blockIdx.x;
  int lb = (bid & 7) * 500 + (bid >> 3);   // 4000 blocks, XCD-chunked, M-major
  int mtb = lb & 15, ntb = lb >> 4;        // 16 x 250
  size_t m0 = (size_t)mtb * 128;
  size_t n0 = (size_t)ntb * 128;
  int t = threadIdx.x, lane = t & 63, wid = t >> 6;
  int wr = (wid >> 1) * 64, wc = (wid & 1) * 64;
  f32x4 acc[4][4] = {};
  for (int k0 = 0; k0 < H_; k0 += 64) {
    // stage A (bf16, direct) + B (fp32 -> bf16, row-major padded)
    #pragma unroll
    for (int i = 0; i < 4; ++i) {
      int idx = i * 256 + t;
      int row = idx >> 3, c8 = (idx & 7) << 3;
      *(short8_t*)&As[row][c8] = *(const short8_t*)(A + (m0 + row) * H_ + k0 + c8);
    }
    #pragma unroll
    for (int i = 0; i < 8; ++i) {
      int f4 = i * 256 + t;
      int kr = f4 >> 5, c4 = (f4 & 31) << 2;
      float4 v = *(const float4*)(W + (size_t)(k0 + kr) * V_ + n0 + c4);
      ushort4 u; u.x = f2bf(v.x); u.y = f2bf(v.y); u.z = f2bf(v.z); u.w = f2bf(v.w);
      *(ushort4*)&Bstage[kr * 132 + c4] = u;
    }
    __syncthreads();
    // assemble transposed B fragments [n][k]
    #pragma unroll
    for (int i = 0; i < 4; ++i) {
      int jj = i * 256 + t;
      int n = jj & 127, k8 = jj >> 7;     // k8 0..7
      short8_t o;
      #pragma unroll
      for (int e = 0; e < 8; ++e) o[e] = (short)Bstage[(k8 * 8 + e) * 132 + n];
      *(short8_t*)&Bs[n][k8 * 8] = o;
    }
    __syncthreads();
    #pragma unroll
    for (int kk = 0; kk < 64; kk += 32) {
      int ko = kk + (lane >> 4) * 8;
      short8_t am[4], bn[4];
      #pragma unroll
      for (int m = 0; m < 4; ++m) am[m] = *(const short8_t*)&As[wr + m * 16 + (lane & 15)][ko];
      #pragma unroll
      for (int n = 0; n < 4; ++n) bn[n] = *(const short8_t*)&Bs[wc + n * 16 + (lane & 15)][ko];
      #pragma unroll
      for (int m = 0; m < 4; ++m)
        #pragma unroll
        for (int n = 0; n < 4; ++n)
          acc[m][n] = __builtin_amdgcn_mfma_f32_16x16x32_bf16(am[m], bn[n], acc[m][n], 0, 0, 0);
    }
    __syncthreads();
  }
  #pragma unroll
  for (int n = 0; n < 4; ++n) {
    int col = (int)n0 + wc + n * 16 + (lane & 15);
    float bv = bias[col];
    #pragma unroll
    for (int m = 0; m < 4; ++m) {
      size_t row = m0 + wr + m * 16 + ((lane >> 4) << 2);
      #pragma unroll
      for (int r = 0; r < 4; ++r)
        C[(row + r) * (size_t)V_ + col] = acc[m][n][r] + bv;
    }
  }
}

// ---------------- persistent decoder kernel ----------------

// relaxed leaf-broadcast barrier (versioned buffers give freshness)
__device__ __forceinline__ void gridbar(int* bar, int target) {
  asm volatile("s_waitcnt vmcnt(0)" ::: "memory");
  __syncthreads();
  if (threadIdx.x == 0) {
    int* leafcnt = bar;
    int* root    = bar + 512;
    int* leafep  = bar + 768;
    int li = blockIdx.x >> 3;
    if (__hip_atomic_fetch_add(&leafcnt[li * 16], 1, __ATOMIC_RELAXED, __HIP_MEMORY_SCOPE_AGENT) == 7) {
      __hip_atomic_store(&leafcnt[li * 16], 0, __ATOMIC_RELAXED, __HIP_MEMORY_SCOPE_AGENT);
      if (__hip_atomic_fetch_add(root, 1, __ATOMIC_RELAXED, __HIP_MEMORY_SCOPE_AGENT) == 31) {
        __hip_atomic_store(root, 0, __ATOMIC_RELAXED, __HIP_MEMORY_SCOPE_AGENT);
        #pragma unroll
        for (int i = 0; i < 32; ++i)
          __hip_atomic_store(&leafep[i * 16], target, __ATOMIC_RELAXED, __HIP_MEMORY_SCOPE_AGENT);
      }
    }
    while (__hip_atomic_load(&leafep[li * 16], __ATOMIC_RELAXED, __HIP_MEMORY_SCOPE_AGENT) != target)
      __builtin_amdgcn_s_sleep(2);
  }
  __syncthreads();
}

#define MFMA16(a, b, c) __builtin_amdgcn_mfma_f32_16x16x32_bf16((a), (b), (c), 0, 0, 0)

__global__ __launch_bounds__(512, 1) void k_mega(
    char* w, u16* __restrict__ dech, float* __restrict__ fout,
    const u16* __restrict__ w2, const u16* __restrict__ wgf,
    const u16* __restrict__ encp, const u16* __restrict__ encT,
    const float* __restrict__ xgr, const float* __restrict__ xg2,
    const float* __restrict__ prev_s, const u16* __restrict__ wlb,
    int* bar, int* mb) {
  const int t = threadIdx.x, blk = blockIdx.x;
  const int lane = t & 63, wid = t >> 6;
  const int l15 = lane & 15, l4 = lane >> 4;
  const int klo = l4 * 8;
  __shared__ short8_t wg_lds[6144];   // 96KB gate weights
  __shared__ f32x4 scr[1024];         // 16KB reduce scratch
  __shared__ float sc[64];
  __shared__ u16 sL[1024];            // s[bb] staging (bf16 hi)
  __shared__ float qL[8 * 17];        // q j-slice, padded stride 17
  int ep = 0;

  for (int i = t; i < 6144; i += 512)
    wg_lds[i] = *(const short8_t*)(wgf + ((size_t)blk * 6144 + i) * 8);

  const int bb = blk >> 3, eg = blk & 7;

  // ---- pinned register operands ----
  const int si_a = t >> 3, jg = t & 7;
  short8_t epv2[2], wlv2[2];
  {
    const u16* p = encp + ((size_t)(bb * 64 + si_a)) * H_ + eg * 128 + jg * 16;
    epv2[0] = *(const short8_t*)(p);     KEEPV(epv2[0]);
    epv2[1] = *(const short8_t*)(p + 8); KEEPV(epv2[1]);
    const u16* q = wlb + eg * 128 + jg * 16;
    wlv2[0] = *(const short8_t*)(q);     KEEPV(wlv2[0]);
    wlv2[1] = *(const short8_t*)(q + 8); KEEPV(wlv2[1]);
  }
  const int eloc = t >> 1, half = t & 1;
  const int ecol = eg * 256 + eloc;
  short8_t et[4];
  #pragma unroll
  for (int i = 0; i < 4; ++i) {
    et[i] = *(const short8_t*)(encT + (size_t)ecol * 2048 + bb * 64 + half * 32 + i * 8);
    KEEPV(et[i]);
  }

  const int pc4 = blk * 8 + l15, jcol = pc4 >> 1, isc = pc4 & 1;
  const int rb = wid * 16 + l4 * 4;
  const bool fin = (wid < 2) && (l15 < 8);
  float sreg[4] = {0.f, 0.f, 0.f, 0.f};

  // P0: init Xs[0] + register state
  {
    int idx = blk * 512 + t;
    u16* xs0h = xs_hi(w, 0);
    u16* xs0l = xs0h + B_ * H_;
    if (idx < B_ * H_) {
      float v = prev_s[idx];
      u16 h = f2bf(v);
      st_u16(&xs0h[idx], h);
      st_u16(&xs0l[idx], f2bf(v - bf2f(h)));
    }
    if (fin) {
      #pragma unroll
      for (int r = 0; r < 4; ++r) sreg[r] = prev_s[(rb + r) * H_ + jcol];
    }
  }
  gridbar(bar, ++ep);

  for (int ts = 0; ts < T_; ++ts) {
    const u16* xsh = xs_hi(w, ts);
    const u16* xsl = xsh + B_ * H_;
    u16* xch = xc_hi(w, ts);
    u16* xcl = xch + B_ * H2_;
    float* spp = spp_v(w, ts);
    int* mbp = mb + (ts * 32 + bb) * 16;

    // (1) stage s[bb] into LDS
    if (t < 128)
      *(short8_t*)&sL[t * 8] = *(const short8_t*)(xsh + bb * H_ + t * 8);
    // (2) step-top prefetches
    float xv[4] = {0.f, 0.f, 0.f, 0.f};
    if (fin) {
      const float* xg = isc ? xg2 : xgr;
      #pragma unroll
      for (int r = 0; r < 4; ++r)
        xv[r] = xg[((size_t)ts * B_ + rb + r) * H_ + jcol];
    }
    short8_t pA[4], pB[4], loA[4], loB[4];
    #pragma unroll
    for (int i = 0; i < 4; ++i) {
      int k = (wid + 8 * i) * 32 + klo;
      pA[i]  = *(const short8_t*)(xsh + l15 * H_ + k);        KEEPV(pA[i]);
      pB[i]  = *(const short8_t*)(xsh + (l15 + 16) * H_ + k); KEEPV(pB[i]);
      loA[i] = *(const short8_t*)(xsl + l15 * H_ + k);        KEEPV(loA[i]);
      loB[i] = *(const short8_t*)(xsl + (l15 + 16) * H_ + k); KEEPV(loB[i]);
    }
    __syncthreads();

    // (3) q j-slice
    {
      const int rot = (t & 3) * 2;
      float qa = 0.f;
      const u16* wp = w2 + ((size_t)(eg * 512 + t)) * 256;
      const u16* sp = sL + (t & 3) * 256;
      #pragma unroll
      for (int i = 0; i < 32; ++i) {
        int ii = (i + rot) & 31;
        short8_t wv = *(const short8_t*)(wp + ii * 8);
        short8_t sv = *(const short8_t*)(sp + ii * 8);
        #pragma unroll
        for (int e = 0; e < 8; ++e)
          qa += bf2f((u16)wv[e]) * bf2f((u16)sv[e]);
      }
      qa += __shfl_xor(qa, 1, 64);
      qa += __shfl_xor(qa, 2, 64);
      if ((t & 3) == 0) { int j = t >> 2; qL[(j >> 4) * 17 + (j & 15)] = qa; }
    }
    __syncthreads();

    // (4) partial scores -> spp
    {
      float p = 0.f;
      #pragma unroll
      for (int jj = 0; jj < 16; ++jj) {
        float qv = qL[jg * 17 + jj];
        p += ftanh(bf2f((u16)epv2[jj >> 3][jj & 7]) + qv) * bf2f((u16)wlv2[jj >> 3][jj & 7]);
      }
      p += __shfl_xor(p, 1, 64);
      p += __shfl_xor(p, 2, 64);
      p += __shfl_xor(p, 4, 64);
      if (jg == 0) st_f32(&spp[(bb * 64 + si_a) * 8 + eg], p);
    }
    asm volatile("s_waitcnt vmcnt(0)" ::: "memory");
    __syncthreads();
    if (t == 0)
      __hip_atomic_fetch_add(mbp, 1, __ATOMIC_RELAXED, __HIP_MEMORY_SCOPE_AGENT);

    // (5) s-part gate MFMAs hoisted pre-barrier
    f32x4 aA = {}, aB = {};
    #pragma unroll
    for (int i = 0; i < 4; ++i) {
      short8_t bv = wg_lds[(wid + 8 * i) * 64 + lane];
      aA = MFMA16(pA[i],  bv, aA);
      aB = MFMA16(pB[i],  bv, aB);
      aA = MFMA16(loA[i], bv, aA);
      aB = MFMA16(loB[i], bv, aB);
    }

    // mini-barrier wait
    if (t == 0) {
      while (__hip_atomic_load(mbp, __ATOMIC_RELAXED, __HIP_MEMORY_SCOPE_AGENT) != 8)
        __builtin_amdgcn_s_sleep(1);
    }
    __syncthreads();

    // (6) phase B: sum partials + softmax + ctx
    if (wid == 0) {
      const float* pp = spp + ((size_t)(bb * 64 + lane)) * 8;
      float4 a0 = *(const float4*)(pp);
      float4 a1 = *(const float4*)(pp + 4);
      float v = (a0.x + a0.y + a0.z + a0.w) + (a1.x + a1.y + a1.z + a1.w);
      float m = v;
      #pragma unroll
      for (int off = 32; off; off >>= 1) m = fmaxf(m, __shfl_xor(m, off, 64));
      float e = __expf(v - m);
      float s = e;
      #pragma unroll
      for (int off = 32; off; off >>= 1) s += __shfl_xor(s, off, 64);
      sc[lane] = e * frcp(s);
    }
    __syncthreads();
    {
      float a = 0.f;
      #pragma unroll
      for (int i = 0; i < 4; ++i)
        #pragma unroll
        for (int j = 0; j < 8; ++j)
          a += sc[half * 32 + i * 8 + j] * bf2f((u16)et[i][j]);
      a += __shfl_xor(a, 1, 64);
      if (half == 0) {
        u16 hh = f2bf(a);
        st_u16(&xch[bb * H2_ + ecol], hh);
        st_u16(&xcl[bb * H2_ + ecol], f2bf(a - bf2f(hh)));
      }
    }
    gridbar(bar, ++ep);

    // (7) P3: Xc-part gate MFMAs + reduce + state update
    {
      #pragma unroll
      for (int i = 4; i < 12; ++i) {
        int kb = wid + 8 * i;
        int k = kb * 32 + klo - H_;
        short8_t hA = *(const short8_t*)(xch + l15 * H2_ + k);
        short8_t lA = *(const short8_t*)(xcl + l15 * H2_ + k);
        short8_t hB = *(const short8_t*)(xch + (l15 + 16) * H2_ + k);
        short8_t lB = *(const short8_t*)(xcl + (l15 + 16) * H2_ + k);
        short8_t bv = wg_lds[kb * 64 + lane];
        aA = MFMA16(hA, bv, aA);
        aA = MFMA16(lA, bv, aA);
        aB = MFMA16(hB, bv, aB);
        aB = MFMA16(lB, bv, aB);
      }
      scr[(wid * 2 + 0) * 64 + lane] = aA;
      scr[(wid * 2 + 1) * 64 + lane] = aB;
      __syncthreads();
      if (wid < 2) {
        f32x4 s = scr[wid * 64 + lane];
        #pragma unroll
        for (int i = 1; i < 8; ++i) s += scr[(i * 2 + wid) * 64 + lane];
        float tot[4];
        #pragma unroll
        for (int r = 0; r < 4; ++r) tot[r] = s[r] + __shfl_xor(s[r], 8, 64);
        if (l15 < 8) {
          u16* nsh = xs_hi(w, ts + 1);
          u16* nsl = nsh + B_ * H_;
          #pragma unroll
          for (int r = 0; r < 4; ++r) {
            int brow = rb + r;
            float pre = tot[r] + xv[r];
            float mate = __shfl_xor(pre, 1, 64);
            float rpre = isc ? mate : pre;
            float cpre = isc ? pre : mate;
            float rg = fsigm(rpre);
            float cg = ftanh(cpre);
            float sp = sreg[r];
            float sn = sp + rg * (cg - sp);
            sreg[r] = sn;
            if (!isc) {
              u16 hh = f2bf(sn);
              st_u16(&nsh[brow * H_ + jcol], hh);
              st_u16(&nsl[brow * H_ + jcol], f2bf(sn - bf2f(hh)));
              dech[((size_t)brow * T_ + ts) * H_ + jcol] = hh;
              if (ts == T_ - 1) fout[brow * H_ + jcol] = sn;
            }
          }
        }
      }
    }
    if (ts != T_ - 1) gridbar(bar, ++ep);   // last-step barrier is dead: kernel-end releases
  }
}

// ---------------- host ----------------

extern "C" void kernel_launch(void* const* d_in, const int* in_sizes, int n_in,
                              void* d_out, int out_size, void* d_ws, size_t ws_size,
                              hipStream_t stream) {
  const float* enc_h    = (const float*)d_in[0];
  const float* prev_s   = (const float*)d_in[1];
  const int*   target   = (const int*)d_in[2];
  const float* embed    = (const float*)d_in[3];
  const float* att_Wenc = (const float*)d_in[4];
  const float* att_benc = (const float*)d_in[5];
  const float* att_Wprev= (const float*)d_in[6];
  const float* att_bprev= (const float*)d_in[7];
  const float* att_wlin = (const float*)d_in[8];
  const float* dc_Wi    = (const float*)d_in[10];
  const float* dc_bi    = (const float*)d_in[11];
  const float* dc_Wh    = (const float*)d_in[12];
  const float* dc_bh    = (const float*)d_in[13];
  const float* dc_Wc    = (const float*)d_in[14];
  const float* dc_bc    = (const float*)d_in[15];
  const float* dc_Wi2   = (const float*)d_in[16];
  const float* dc_bi2   = (const float*)d_in[17];
  const float* dc_Wh2   = (const float*)d_in[18];
  const float* dc_bh2   = (const float*)d_in[19];
  const float* dc_Wc2   = (const float*)d_in[20];
  const float* dc_bc2   = (const float*)d_in[21];
  const float* out_W    = (const float*)d_in[22];
  const float* out_b    = (const float*)d_in[23];

  char* w = (char*)d_ws;
  float* x    = (float*)(w + X_OFF);
  float* xgr  = (float*)(w + XGR_OFF);
  float* xg2  = (float*)(w + XG2_OFF);
  u16*  encT  = (u16*)(w + ENCT_OFF);
  u16*  encp  = (u16*)(w + ENCP_OFF);
  u16*  w2    = (u16*)(w + W2_OFF);
  u16*  wgf   = (u16*)(w + WGF_OFF);
  u16*  dech  = (u16*)(w + DECH_OFF);
  u16*  wlb   = (u16*)(w + WLB_OFF);
  float* bcr  = (float*)(w + BCR_OFF);
  float* bc2  = (float*)(w + BC2_OFF);
  int*  bar   = (int*)(w + BAR_OFF);
  int*  mb    = (int*)(w + MB_OFF);
  float* fout = (float*)d_out + (size_t)BT_ * V_;

  hipMemsetAsync(w + MB_OFF, 0, 136 * KB_, stream);   // mb + bar

  // prologue: 2 launches
  k_prep<<<5764, 256, 0, stream>>>(x, embed, target, encT, enc_h,
                                   w2, att_Wprev, wgf, dc_Wh, dc_Wc, dc_Wh2, dc_Wc2,
                                   encp, att_Wenc, att_benc, att_bprev,
                                   bcr, bc2, wlb,
                                   dc_bi, dc_bh, dc_bc, dc_bi2, dc_bh2, dc_bc2, att_wlin);
  k_gemm12<<<256, 256, 0, stream>>>(x, dc_Wi, dc_Wi2, xgr, xg2, bcr, bc2);

  // 64-step recurrence
  k_mega<<<256, 512, 0, stream>>>(w, dech, fout,
                                  w2, wgf, encp, encT, xgr, xg2,
                                  prev_s, wlb, bar, mb);

  // fused vocab projection: one launch, in-kernel B transpose (no wot/wtrans)
  k_gemm2d<<<4000, 256, 0, stream>>>(dech, out_W, (float*)d_out, out_b);
}

// Round 12
// 2799.029 us; speedup vs baseline: 1.0340x; 1.0340x over previous
//
#include <hip/hip_runtime.h>

// Sizes
#define B_   32
#define S_   64
#define T_   64
#define H_   1024
#define H2_  2048
#define E_   512
#define V_   32000
#define K3_  3072
#define BT_  2048

typedef unsigned short u16;
typedef __attribute__((ext_vector_type(8))) short short8_t;  // 8 x bf16
typedef __attribute__((ext_vector_type(4))) float f32x4;

__device__ __forceinline__ u16 f2bf(float f) {
  unsigned x = __float_as_uint(f);
  unsigned r = (x + 0x7fffu + ((x >> 16) & 1u)) >> 16;  // RNE
  return (u16)r;
}
__device__ __forceinline__ float bf2f(u16 h) {
  return __uint_as_float(((unsigned)h) << 16);
}
__device__ __forceinline__ float frcp(float x) { return __builtin_amdgcn_rcpf(x); }
__device__ __forceinline__ float ftanh(float x) {
  float e = __expf(2.f * x);
  return 1.f - 2.f * frcp(e + 1.f);
}
__device__ __forceinline__ float fsigm(float x) {
  return frcp(1.f + __expf(-x));
}

#define KEEPV(x) asm volatile("" : "+v"(x))

__device__ __forceinline__ void st_u16(u16* p, u16 v) {
  __hip_atomic_store(p, v, __ATOMIC_RELAXED, __HIP_MEMORY_SCOPE_AGENT);
}
__device__ __forceinline__ void st_f32(float* p, float v) {
  __hip_atomic_store(p, v, __ATOMIC_RELAXED, __HIP_MEMORY_SCOPE_AGENT);
}

// ---------------- workspace layout (bytes) ----------------
#define MB_ (1ull << 20)
#define KB_ (1ull << 10)
#define X_OFF    (0)               // 4MB x (pre-loop) / spp versions (loop) / wot (post)
#define SPP_OFF  (0)               // 64 versions x 64KB
#define XGR_OFF  (4*MB_)           // 8MB (persistent through loop)
#define XG2_OFF  (12*MB_)          // 8MB
#define ENCT_OFF (20*MB_)          // 8MB pre-loop (pinned) — aliased by Xc in loop
#define XCV_OFF  (20*MB_)          // Xc versions t=0..63 x 256KB -> [20,36)
#define ENCP_OFF (28*MB_)          // 4MB pre-loop (pinned)
#define W2_OFF   (36*MB_)          // 2MB Wprev slices (persistent)
#define WGF_OFF  (38*MB_)          // 24MB pre-loop -> [38,62); aliased by Xs/dech
#define XSV_OFF  (38*MB_)          // Xs versions t=1..64 x 128KB -> [38,46)
#define DECH_OFF (46*MB_)          // 4MB (persistent until gemm2)
#define WOT_OFF  (0)               // 32MB (post-loop only; spp dead by then)
#define XS0_OFF  (62*MB_)          // 128KB
#define MB_OFF   (62*MB_ + 128*KB_)  // 128KB mini-bar counters
#define BAR_OFF  (62*MB_ + 256*KB_)  // 8KB
#define WLB_OFF  (62*MB_ + 272*KB_)  // 2KB
#define BCR_OFF  (62*MB_ + 276*KB_)  // 4KB
#define BC2_OFF  (62*MB_ + 280*KB_)  // 4KB

__device__ __forceinline__ u16* xs_hi(char* w, int t) {
  return (u16*)(t == 0 ? (w + XS0_OFF) : (w + XSV_OFF + (size_t)(t - 1) * 131072));
}
__device__ __forceinline__ u16* xc_hi(char* w, int t) {
  return (u16*)(w + XCV_OFF + (size_t)t * 262144);
}
__device__ __forceinline__ float* spp_v(char* w, int t) {
  return (float*)(w + SPP_OFF + (size_t)t * 65536);
}

// ---------------- shared GEMM body (prologue) ----------------
__device__ void gemm_body(char* smemRaw,
                          const float* __restrict__ A, int lda,
                          const float* __restrict__ Bm, int ldb,
                          void* __restrict__ Cv, int ldc, int outBf16,
                          const float* __restrict__ bias, const float* __restrict__ bias2,
                          int mtiles, int ntiles, int K, int bid) {
  u16 (*As)[72] = (u16(*)[72])smemRaw;
  u16 (*Bs)[72] = (u16(*)[72])(smemRaw + 128 * 72 * 2);
  int nwg = mtiles * ntiles;
  int cpx = nwg >> 3;
  int lb = (bid & 7) * cpx + (bid >> 3);
  int ntb = lb / mtiles, mtb = lb - ntb * mtiles;
  size_t m0 = (size_t)mtb * 128, n0 = (size_t)ntb * 128;
  int t = threadIdx.x, lane = t & 63, wid = t >> 6;
  int wr = (wid >> 1) * 64, wc = (wid & 1) * 64;
  f32x4 acc[4][4] = {};
  for (int k0 = 0; k0 < K; k0 += 64) {
    #pragma unroll
    for (int i = 0; i < 8; ++i) {
      int f4 = i * 256 + t;
      int row = f4 >> 4, c4 = (f4 & 15) << 2;
      float4 v = *(const float4*)(A + (m0 + row) * (size_t)lda + k0 + c4);
      ushort4 u; u.x = f2bf(v.x); u.y = f2bf(v.y); u.z = f2bf(v.z); u.w = f2bf(v.w);
      *(ushort4*)&As[row][c4] = u;
    }
    #pragma unroll
    for (int i = 0; i < 8; ++i) {
      int f4 = i * 256 + t;
      int kr = f4 >> 5, c4 = (f4 & 31) << 2;
      float4 v = *(const float4*)(Bm + (size_t)(k0 + kr) * ldb + n0 + c4);
      Bs[c4 + 0][kr] = f2bf(v.x);
      Bs[c4 + 1][kr] = f2bf(v.y);
      Bs[c4 + 2][kr] = f2bf(v.z);
      Bs[c4 + 3][kr] = f2bf(v.w);
    }
    __syncthreads();
    #pragma unroll
    for (int kk = 0; kk < 64; kk += 32) {
      int ko = kk + (lane >> 4) * 8;
      short8_t am[4], bn[4];
      #pragma unroll
      for (int m = 0; m < 4; ++m) am[m] = *(const short8_t*)&As[wr + m * 16 + (lane & 15)][ko];
      #pragma unroll
      for (int n = 0; n < 4; ++n) bn[n] = *(const short8_t*)&Bs[wc + n * 16 + (lane & 15)][ko];
      #pragma unroll
      for (int m = 0; m < 4; ++m)
        #pragma unroll
        for (int n = 0; n < 4; ++n)
          acc[m][n] = __builtin_amdgcn_mfma_f32_16x16x32_bf16(am[m], bn[n], acc[m][n], 0, 0, 0);
    }
    __syncthreads();
  }
  #pragma unroll
  for (int n = 0; n < 4; ++n) {
    int col = wc + n * 16 + (lane & 15);
    float bv = bias ? bias[n0 + col] : 0.f;
    if (bias2) bv += bias2[n0 + col];
    #pragma unroll
    for (int m = 0; m < 4; ++m) {
      size_t row = m0 + wr + m * 16 + ((lane >> 4) << 2);
      #pragma unroll
      for (int r = 0; r < 4; ++r) {
        float val = acc[m][n][r] + bv;
        if (outBf16) ((u16*)Cv)[(row + r) * (size_t)ldc + n0 + col] = f2bf(val);
        else ((float*)Cv)[(row + r) * (size_t)ldc + n0 + col] = val;
      }
    }
  }
}

// ---------------- merged prologue ----------------
__global__ __launch_bounds__(256) void k_prep(
    float* __restrict__ x, const float* __restrict__ embed, const int* __restrict__ tgt,
    u16* __restrict__ encT, const float* __restrict__ enc_h,
    u16* __restrict__ w2, const float* __restrict__ Wprev,
    u16* __restrict__ wgf, const float* __restrict__ Wh, const float* __restrict__ Wc,
    const float* __restrict__ Wh2, const float* __restrict__ Wc2,
    u16* __restrict__ encp, const float* __restrict__ Wenc,
    const float* __restrict__ benc, const float* __restrict__ bprev,
    float* __restrict__ bcr, float* __restrict__ bc2o, u16* __restrict__ wlb,
    const float* __restrict__ bi, const float* __restrict__ bh, const float* __restrict__ bc,
    const float* __restrict__ bi2, const float* __restrict__ bh2, const float* __restrict__ bc2i,
    const float* __restrict__ wlin) {
  __shared__ char pbuf[36864];
  const int bid = blockIdx.x, t = threadIdx.x;

  if (bid < 1024) {
    int f4id = bid * 256 + t;
    int row = f4id >> 7, c4 = f4id & 127;
    int tt = row >> 5, bbb = row & 31;
    int trow = tgt[bbb * T_ + tt];
    ((float4*)x)[(size_t)row * 128 + c4] = ((const float4*)embed)[(size_t)trow * 128 + c4];
  } else if (bid < 2048) {
    u16 (*ld)[68] = (u16(*)[68])pbuf;
    int teb = bid - 1024;
    int b = teb >> 5, et = teb & 31;
    int e0 = et * 64;
    #pragma unroll
    for (int i = 0; i < 4; ++i) {
      int f4 = i * 256 + t;
      int si = f4 >> 4, e4 = (f4 & 15) << 2;
      float4 v = *(const float4*)(enc_h + ((size_t)(b * 64 + si)) * H2_ + e0 + e4);
      ld[si][e4 + 0] = f2bf(v.x); ld[si][e4 + 1] = f2bf(v.y);
      ld[si][e4 + 2] = f2bf(v.z); ld[si][e4 + 3] = f2bf(v.w);
    }
    __syncthreads();
    #pragma unroll
    for (int i = 0; i < 2; ++i) {
      int idx = i * 256 + t;
      int e = idx >> 3, s8 = (idx & 7) << 3;
      short8_t o;
      #pragma unroll
      for (int k = 0; k < 8; ++k) o[k] = (short)ld[s8 + k][e];
      *(short8_t*)(encT + ((size_t)(e0 + e)) * 2048 + b * 64 + s8) = o;
    }
  } else if (bid < 2560) {
    float (*ld)[33] = (float(*)[33])pbuf;
    int pb = bid - 2048;
    int kt = pb >> 5, jt = pb & 31;
    int k0 = kt * 64, j0 = jt * 32;
    #pragma unroll
    for (int i = 0; i < 8; ++i) {
      int idx = i * 256 + t; int kr = idx >> 5, jc = idx & 31;
      ld[kr][jc] = Wprev[(size_t)(k0 + kr) * H_ + j0 + jc];
    }
    __syncthreads();
    int jloc = t >> 3, kk8 = t & 7;
    int j = j0 + jloc;
    int eg = j >> 7;
    int th = ((j & 127) << 2) | (kt >> 2);
    int i = ((kt & 3) << 3) | kk8;
    short8_t o;
    #pragma unroll
    for (int e = 0; e < 8; ++e) o[e] = (short)f2bf(ld[kk8 * 8 + e][jloc]);
    *(short8_t*)(w2 + ((size_t)((eg * 512 + th) * 32 + i)) * 8) = o;
  } else if (bid < 5632) {
    float (*ld)[33] = (float(*)[33])pbuf;
    int pgb = bid - 2560;
    int sel = pgb & 1;
    int jt  = (pgb >> 1) & 31;
    int kt  = pgb >> 6;
    int k0 = kt * 64, j0 = jt * 32;
    const float* srcW = (k0 < H_) ? (sel ? Wh2 : Wh) : (sel ? Wc2 : Wc);
    int ldw = sel ? H_ : H2_;
    int koff = (k0 < H_) ? k0 : (k0 - H_);
    #pragma unroll
    for (int i = 0; i < 8; ++i) {
      int idx = i * 256 + t; int kr = idx >> 5, jc = idx & 31;
      ld[kr][jc] = srcW[(size_t)(koff + kr) * ldw + j0 + jc];
    }
    __syncthreads();
    #pragma unroll
    for (int it = 0; it < 2; ++it) {
      int u = it * 256 + t;
      int m = u & 3, sub = (u >> 2) & 3, kbl = (u >> 4) & 1, islo = (u >> 5) & 1, gg = u >> 6;
      int jjLoc = gg * 4 + m;
      int p = 2 * (j0 + jjLoc) + sel;
      int g = p >> 3, cc = p & 7;
      int c = cc + 8 * islo;
      int KB = kt * 2 + kbl;
      size_t lin = ((size_t)(g * 96 + KB) * 4 + sub) * 16 + c;
      short8_t o;
      #pragma unroll
      for (int j = 0; j < 8; ++j) {
        float v = ld[kbl * 32 + sub * 8 + j][jjLoc];
        u16 h = f2bf(v);
        o[j] = (short)(islo ? f2bf(v - bf2f(h)) : h);
      }
      *(short8_t*)(wgf + lin * 8) = o;
    }
  } else if (bid < 5760) {
    gemm_body(pbuf, enc_h, H2_, Wenc, H_, encp, H_, 1, benc, bprev, 16, 8, H2_, bid - 5632);
  } else {
    int j = (bid - 5760) * 256 + t;
    if (j < H_) {
      bcr[j]  = bi[j]  + bh[j]  + bc[j];
      bc2o[j] = bi2[j] + bh2[j] + bc2i[j];
      wlb[j]  = f2bf(wlin[j]);
    }
  }
}

__global__ __launch_bounds__(256) void k_gemm12(
    const float* __restrict__ x,
    const float* __restrict__ Wi, const float* __restrict__ Wi2,
    float* __restrict__ xgr, float* __restrict__ xg2,
    const float* __restrict__ bcr, const float* __restrict__ bc2) {
  __shared__ char pbuf[36864];
  if (blockIdx.x < 128)
    gemm_body(pbuf, x, E_, Wi, H2_, xgr, H_, 0, bcr, nullptr, 16, 8, E_, blockIdx.x);
  else
    gemm_body(pbuf, x, E_, Wi2, H_, xg2, H_, 0, bc2, nullptr, 16, 8, E_, blockIdx.x - 128);
}

// out_W half -> wot bf16 [nLocal 16000][k 1024]
__global__ __launch_bounds__(256) void k_wtrans(u16* __restrict__ wot,
                                                const float* __restrict__ W, int nbase) {
  __shared__ u16 ld[64][68];
  int nt = blockIdx.x % 250, kt = blockIdx.x / 250;
  int n0 = nbase + nt * 64, k0 = kt * 64;
  int t = threadIdx.x;
  #pragma unroll
  for (int i = 0; i < 4; ++i) {
    int f4 = i * 256 + t;
    int kr = f4 >> 4, n4 = (f4 & 15) << 2;
    float4 v = *(const float4*)(W + (size_t)(k0 + kr) * V_ + n0 + n4);
    ld[kr][n4 + 0] = f2bf(v.x); ld[kr][n4 + 1] = f2bf(v.y);
    ld[kr][n4 + 2] = f2bf(v.z); ld[kr][n4 + 3] = f2bf(v.w);
  }
  __syncthreads();
  #pragma unroll
  for (int i = 0; i < 2; ++i) {
    int idx = i * 256 + t;
    int n = idx >> 3, k8 = (idx & 7) << 3;
    short8_t o;
    #pragma unroll
    for (int k = 0; k < 8; ++k) o[k] = (short)ld[k8 + k][n];
    *(short8_t*)(wot + ((size_t)(nt * 64 + n)) * H_ + k0 + k8) = o;
  }
}

// final GEMM: dech bf16 [2048][1024] @ wot^T -> C fp32 (per 16000-col half)
__global__ __launch_bounds__(256) void k_gemm2(
    const u16* __restrict__ A, const u16* __restrict__ Bt,
    float* __restrict__ C, const float* __restrict__ bias, int n0g) {
  __shared__ u16 As[128][72];
  __shared__ u16 Bs[128][72];
  int bid = blockIdx.x;
  int lb = (bid & 7) * 250 + (bid >> 3);
  int mtb = lb & 15, ntb = lb >> 4;
  size_t m0 = (size_t)mtb * 128;
  size_t nl0 = (size_t)ntb * 128;
  int t = threadIdx.x, lane = t & 63, wid = t >> 6;
  int wr = (wid >> 1) * 64, wc = (wid & 1) * 64;
  f32x4 acc[4][4] = {};
  for (int k0 = 0; k0 < H_; k0 += 64) {
    #pragma unroll
    for (int i = 0; i < 4; ++i) {
      int idx = i * 256 + t;
      int row = idx >> 3, c8 = (idx & 7) << 3;
      *(short8_t*)&As[row][c8] = *(const short8_t*)(A + (m0 + row) * H_ + k0 + c8);
      *(short8_t*)&Bs[row][c8] = *(const short8_t*)(Bt + (nl0 + row) * H_ + k0 + c8);
    }
    __syncthreads();
    #pragma unroll
    for (int kk = 0; kk < 64; kk += 32) {
      int ko = kk + (lane >> 4) * 8;
      short8_t am[4], bn[4];
      #pragma unroll
      for (int m = 0; m < 4; ++m) am[m] = *(const short8_t*)&As[wr + m * 16 + (lane & 15)][ko];
      #pragma unroll
      for (int n = 0; n < 4; ++n) bn[n] = *(const short8_t*)&Bs[wc + n * 16 + (lane & 15)][ko];
      #pragma unroll
      for (int m = 0; m < 4; ++m)
        #pragma unroll
        for (int n = 0; n < 4; ++n)
          acc[m][n] = __builtin_amdgcn_mfma_f32_16x16x32_bf16(am[m], bn[n], acc[m][n], 0, 0, 0);
    }
    __syncthreads();
  }
  #pragma unroll
  for (int n = 0; n < 4; ++n) {
    int col = n0g + (int)nl0 + wc + n * 16 + (lane & 15);
    float bv = bias[col];
    #pragma unroll
    for (int m = 0; m < 4; ++m) {
      size_t row = m0 + wr + m * 16 + ((lane >> 4) << 2);
      #pragma unroll
      for (int r = 0; r < 4; ++r)
        C[(row + r) * (size_t)V_ + col] = acc[m][n][r] + bv;
    }
  }
}

// ---------------- persistent decoder kernel ----------------

// relaxed leaf-broadcast barrier (versioned buffers give freshness)
__device__ __forceinline__ void gridbar(int* bar, int target) {
  asm volatile("s_waitcnt vmcnt(0)" ::: "memory");
  __syncthreads();
  if (threadIdx.x == 0) {
    int* leafcnt = bar;
    int* root    = bar + 512;
    int* leafep  = bar + 768;
    int li = blockIdx.x >> 3;
    if (__hip_atomic_fetch_add(&leafcnt[li * 16], 1, __ATOMIC_RELAXED, __HIP_MEMORY_SCOPE_AGENT) == 7) {
      __hip_atomic_store(&leafcnt[li * 16], 0, __ATOMIC_RELAXED, __HIP_MEMORY_SCOPE_AGENT);
      if (__hip_atomic_fetch_add(root, 1, __ATOMIC_RELAXED, __HIP_MEMORY_SCOPE_AGENT) == 31) {
        __hip_atomic_store(root, 0, __ATOMIC_RELAXED, __HIP_MEMORY_SCOPE_AGENT);
        #pragma unroll
        for (int i = 0; i < 32; ++i)
          __hip_atomic_store(&leafep[i * 16], target, __ATOMIC_RELAXED, __HIP_MEMORY_SCOPE_AGENT);
      }
    }
    while (__hip_atomic_load(&leafep[li * 16], __ATOMIC_RELAXED, __HIP_MEMORY_SCOPE_AGENT) != target)
      __builtin_amdgcn_s_sleep(2);
  }
  __syncthreads();
}

#define MFMA16(a, b, c) __builtin_amdgcn_mfma_f32_16x16x32_bf16((a), (b), (c), 0, 0, 0)

__global__ __launch_bounds__(512, 1) void k_mega(
    char* w, u16* __restrict__ dech, float* __restrict__ fout,
    const u16* __restrict__ w2, const u16* __restrict__ wgf,
    const u16* __restrict__ encp, const u16* __restrict__ encT,
    const float* __restrict__ xgr, const float* __restrict__ xg2,
    const float* __restrict__ prev_s, const u16* __restrict__ wlb,
    int* bar, int* mb) {
  const int t = threadIdx.x, blk = blockIdx.x;
  const int lane = t & 63, wid = t >> 6;
  const int l15 = lane & 15, l4 = lane >> 4;
  const int klo = l4 * 8;
  __shared__ short8_t wg_lds[6144];   // 96KB gate weights
  __shared__ f32x4 scr[1024];         // 16KB reduce scratch
  __shared__ float sc[64];
  __shared__ u16 sL[1024];            // s[bb] staging (bf16 hi)
  __shared__ float qL[8 * 17];        // q j-slice, padded stride 17
  int ep = 0;

  for (int i = t; i < 6144; i += 512)
    wg_lds[i] = *(const short8_t*)(wgf + ((size_t)blk * 6144 + i) * 8);

  const int bb = blk >> 3, eg = blk & 7;

  // ---- pinned register operands ----
  const int si_a = t >> 3, jg = t & 7;
  short8_t epv2[2], wlv2[2];
  {
    const u16* p = encp + ((size_t)(bb * 64 + si_a)) * H_ + eg * 128 + jg * 16;
    epv2[0] = *(const short8_t*)(p);     KEEPV(epv2[0]);
    epv2[1] = *(const short8_t*)(p + 8); KEEPV(epv2[1]);
    const u16* q = wlb + eg * 128 + jg * 16;
    wlv2[0] = *(const short8_t*)(q);     KEEPV(wlv2[0]);
    wlv2[1] = *(const short8_t*)(q + 8); KEEPV(wlv2[1]);
  }
  const int eloc = t >> 1, half = t & 1;
  const int ecol = eg * 256 + eloc;
  short8_t et[4];
  #pragma unroll
  for (int i = 0; i < 4; ++i) {
    et[i] = *(const short8_t*)(encT + (size_t)ecol * 2048 + bb * 64 + half * 32 + i * 8);
    KEEPV(et[i]);
  }

  const int pc4 = blk * 8 + l15, jcol = pc4 >> 1, isc = pc4 & 1;
  const int rb = wid * 16 + l4 * 4;
  const bool fin = (wid < 2) && (l15 < 8);
  float sreg[4] = {0.f, 0.f, 0.f, 0.f};

  // P0: init Xs[0] + register state
  {
    int idx = blk * 512 + t;
    u16* xs0h = xs_hi(w, 0);
    u16* xs0l = xs0h + B_ * H_;
    if (idx < B_ * H_) {
      float v = prev_s[idx];
      u16 h = f2bf(v);
      st_u16(&xs0h[idx], h);
      st_u16(&xs0l[idx], f2bf(v - bf2f(h)));
    }
    if (fin) {
      #pragma unroll
      for (int r = 0; r < 4; ++r) sreg[r] = prev_s[(rb + r) * H_ + jcol];
    }
  }
  gridbar(bar, ++ep);

  for (int ts = 0; ts < T_; ++ts) {
    const u16* xsh = xs_hi(w, ts);
    const u16* xsl = xsh + B_ * H_;
    u16* xch = xc_hi(w, ts);
    u16* xcl = xch + B_ * H2_;
    float* spp = spp_v(w, ts);
    int* mbp = mb + (ts * 32 + bb) * 16;

    // (1) stage s[bb] into LDS
    if (t < 128)
      *(short8_t*)&sL[t * 8] = *(const short8_t*)(xsh + bb * H_ + t * 8);
    // (2) step-top prefetches
    float xv[4] = {0.f, 0.f, 0.f, 0.f};
    if (fin) {
      const float* xg = isc ? xg2 : xgr;
      #pragma unroll
      for (int r = 0; r < 4; ++r)
        xv[r] = xg[((size_t)ts * B_ + rb + r) * H_ + jcol];
    }
    short8_t pA[4], pB[4], loA[4], loB[4];
    #pragma unroll
    for (int i = 0; i < 4; ++i) {
      int k = (wid + 8 * i) * 32 + klo;
      pA[i]  = *(const short8_t*)(xsh + l15 * H_ + k);        KEEPV(pA[i]);
      pB[i]  = *(const short8_t*)(xsh + (l15 + 16) * H_ + k); KEEPV(pB[i]);
      loA[i] = *(const short8_t*)(xsl + l15 * H_ + k);        KEEPV(loA[i]);
      loB[i] = *(const short8_t*)(xsl + (l15 + 16) * H_ + k); KEEPV(loB[i]);
    }
    __syncthreads();

    // (3) q j-slice
    {
      const int rot = (t & 3) * 2;
      float qa = 0.f;
      const u16* wp = w2 + ((size_t)(eg * 512 + t)) * 256;
      const u16* sp = sL + (t & 3) * 256;
      #pragma unroll
      for (int i = 0; i < 32; ++i) {
        int ii = (i + rot) & 31;
        short8_t wv = *(const short8_t*)(wp + ii * 8);
        short8_t sv = *(const short8_t*)(sp + ii * 8);
        #pragma unroll
        for (int e = 0; e < 8; ++e)
          qa += bf2f((u16)wv[e]) * bf2f((u16)sv[e]);
      }
      qa += __shfl_xor(qa, 1, 64);
      qa += __shfl_xor(qa, 2, 64);
      if ((t & 3) == 0) { int j = t >> 2; qL[(j >> 4) * 17 + (j & 15)] = qa; }
    }
    __syncthreads();

    // (4) partial scores -> spp
    {
      float p = 0.f;
      #pragma unroll
      for (int jj = 0; jj < 16; ++jj) {
        float qv = qL[jg * 17 + jj];
        p += ftanh(bf2f((u16)epv2[jj >> 3][jj & 7]) + qv) * bf2f((u16)wlv2[jj >> 3][jj & 7]);
      }
      p += __shfl_xor(p, 1, 64);
      p += __shfl_xor(p, 2, 64);
      p += __shfl_xor(p, 4, 64);
      if (jg == 0) st_f32(&spp[(bb * 64 + si_a) * 8 + eg], p);
    }
    asm volatile("s_waitcnt vmcnt(0)" ::: "memory");
    __syncthreads();
    if (t == 0)
      __hip_atomic_fetch_add(mbp, 1, __ATOMIC_RELAXED, __HIP_MEMORY_SCOPE_AGENT);

    // (5) s-part gate MFMAs hoisted pre-barrier
    f32x4 aA = {}, aB = {};
    #pragma unroll
    for (int i = 0; i < 4; ++i) {
      short8_t bv = wg_lds[(wid + 8 * i) * 64 + lane];
      aA = MFMA16(pA[i],  bv, aA);
      aB = MFMA16(pB[i],  bv, aB);
      aA = MFMA16(loA[i], bv, aA);
      aB = MFMA16(loB[i], bv, aB);
    }

    // mini-barrier wait
    if (t == 0) {
      while (__hip_atomic_load(mbp, __ATOMIC_RELAXED, __HIP_MEMORY_SCOPE_AGENT) != 8)
        __builtin_amdgcn_s_sleep(1);
    }
    __syncthreads();

    // (6) phase B: sum partials + softmax + ctx
    if (wid == 0) {
      const float* pp = spp + ((size_t)(bb * 64 + lane)) * 8;
      float4 a0 = *(const float4*)(pp);
      float4 a1 = *(const float4*)(pp + 4);
      float v = (a0.x + a0.y + a0.z + a0.w) + (a1.x + a1.y + a1.z + a1.w);
      float m = v;
      #pragma unroll
      for (int off = 32; off; off >>= 1) m = fmaxf(m, __shfl_xor(m, off, 64));
      float e = __expf(v - m);
      float s = e;
      #pragma unroll
      for (int off = 32; off; off >>= 1) s += __shfl_xor(s, off, 64);
      sc[lane] = e * frcp(s);
    }
    __syncthreads();
    {
      float a = 0.f;
      #pragma unroll
      for (int i = 0; i < 4; ++i)
        #pragma unroll
        for (int j = 0; j < 8; ++j)
          a += sc[half * 32 + i * 8 + j] * bf2f((u16)et[i][j]);
      a += __shfl_xor(a, 1, 64);
      if (half == 0) {
        u16 hh = f2bf(a);
        st_u16(&xch[bb * H2_ + ecol], hh);
        st_u16(&xcl[bb * H2_ + ecol], f2bf(a - bf2f(hh)));
      }
    }
    gridbar(bar, ++ep);

    // (7) P3: Xc-part gate MFMAs + reduce + state update
    {
      #pragma unroll
      for (int i = 4; i < 12; ++i) {
        int kb = wid + 8 * i;
        int k = kb * 32 + klo - H_;
        short8_t hA = *(const short8_t*)(xch + l15 * H2_ + k);
        short8_t lA = *(const short8_t*)(xcl + l15 * H2_ + k);
        short8_t hB = *(const short8_t*)(xch + (l15 + 16) * H2_ + k);
        short8_t lB = *(const short8_t*)(xcl + (l15 + 16) * H2_ + k);
        short8_t bv = wg_lds[kb * 64 + lane];
        aA = MFMA16(hA, bv, aA);
        aA = MFMA16(lA, bv, aA);
        aB = MFMA16(hB, bv, aB);
        aB = MFMA16(lB, bv, aB);
      }
      scr[(wid * 2 + 0) * 64 + lane] = aA;
      scr[(wid * 2 + 1) * 64 + lane] = aB;
      __syncthreads();
      if (wid < 2) {
        f32x4 s = scr[wid * 64 + lane];
        #pragma unroll
        for (int i = 1; i < 8; ++i) s += scr[(i * 2 + wid) * 64 + lane];
        float tot[4];
        #pragma unroll
        for (int r = 0; r < 4; ++r) tot[r] = s[r] + __shfl_xor(s[r], 8, 64);
        if (l15 < 8) {
          u16* nsh = xs_hi(w, ts + 1);
          u16* nsl = nsh + B_ * H_;
          #pragma unroll
          for (int r = 0; r < 4; ++r) {
            int brow = rb + r;
            float pre = tot[r] + xv[r];
            float mate = __shfl_xor(pre, 1, 64);
            float rpre = isc ? mate : pre;
            float cpre = isc ? pre : mate;
            float rg = fsigm(rpre);
            float cg = ftanh(cpre);
            float sp = sreg[r];
            float sn = sp + rg * (cg - sp);
            sreg[r] = sn;
            if (!isc) {
              u16 hh = f2bf(sn);
              st_u16(&nsh[brow * H_ + jcol], hh);
              st_u16(&nsl[brow * H_ + jcol], f2bf(sn - bf2f(hh)));
              dech[((size_t)brow * T_ + ts) * H_ + jcol] = hh;
              if (ts == T_ - 1) fout[brow * H_ + jcol] = sn;
            }
          }
        }
      }
    }
    if (ts != T_ - 1) gridbar(bar, ++ep);   // last-step barrier dead: kernel-end releases
  }
}

// ---------------- host ----------------

extern "C" void kernel_launch(void* const* d_in, const int* in_sizes, int n_in,
                              void* d_out, int out_size, void* d_ws, size_t ws_size,
                              hipStream_t stream) {
  const float* enc_h    = (const float*)d_in[0];
  const float* prev_s   = (const float*)d_in[1];
  const int*   target   = (const int*)d_in[2];
  const float* embed    = (const float*)d_in[3];
  const float* att_Wenc = (const float*)d_in[4];
  const float* att_benc = (const float*)d_in[5];
  const float* att_Wprev= (const float*)d_in[6];
  const float* att_bprev= (const float*)d_in[7];
  const float* att_wlin = (const float*)d_in[8];
  const float* dc_Wi    = (const float*)d_in[10];
  const float* dc_bi    = (const float*)d_in[11];
  const float* dc_Wh    = (const float*)d_in[12];
  const float* dc_bh    = (const float*)d_in[13];
  const float* dc_Wc    = (const float*)d_in[14];
  const float* dc_bc    = (const float*)d_in[15];
  const float* dc_Wi2   = (const float*)d_in[16];
  const float* dc_bi2   = (const float*)d_in[17];
  const float* dc_Wh2   = (const float*)d_in[18];
  const float* dc_bh2   = (const float*)d_in[19];
  const float* dc_Wc2   = (const float*)d_in[20];
  const float* dc_bc2   = (const float*)d_in[21];
  const float* out_W    = (const float*)d_in[22];
  const float* out_b    = (const float*)d_in[23];

  char* w = (char*)d_ws;
  float* x    = (float*)(w + X_OFF);
  float* xgr  = (float*)(w + XGR_OFF);
  float* xg2  = (float*)(w + XG2_OFF);
  u16*  encT  = (u16*)(w + ENCT_OFF);
  u16*  encp  = (u16*)(w + ENCP_OFF);
  u16*  w2    = (u16*)(w + W2_OFF);
  u16*  wgf   = (u16*)(w + WGF_OFF);
  u16*  wot   = (u16*)(w + WOT_OFF);
  u16*  dech  = (u16*)(w + DECH_OFF);
  u16*  wlb   = (u16*)(w + WLB_OFF);
  float* bcr  = (float*)(w + BCR_OFF);
  float* bc2  = (float*)(w + BC2_OFF);
  int*  bar   = (int*)(w + BAR_OFF);
  int*  mb    = (int*)(w + MB_OFF);
  float* fout = (float*)d_out + (size_t)BT_ * V_;

  hipMemsetAsync(w + MB_OFF, 0, 136 * KB_, stream);   // mb + bar

  // prologue: 2 launches
  k_prep<<<5764, 256, 0, stream>>>(x, embed, target, encT, enc_h,
                                   w2, att_Wprev, wgf, dc_Wh, dc_Wc, dc_Wh2, dc_Wc2,
                                   encp, att_Wenc, att_benc, att_bprev,
                                   bcr, bc2, wlb,
                                   dc_bi, dc_bh, dc_bc, dc_bi2, dc_bh2, dc_bc2, att_wlin);
  k_gemm12<<<256, 256, 0, stream>>>(x, dc_Wi, dc_Wi2, xgr, xg2, bcr, bc2);

  // 64-step recurrence: 2 full barriers + 1 per-b mini-barrier per step
  k_mega<<<256, 512, 0, stream>>>(w, dech, fout,
                                  w2, wgf, encp, encT, xgr, xg2,
                                  prev_s, wlb, bar, mb);

  // vocab projection in two halves (wot aliases dead loop workspace)
  k_wtrans<<<4000, 256, 0, stream>>>(wot, out_W, 0);
  k_gemm2 <<<2000, 256, 0, stream>>>(dech, wot, (float*)d_out, out_b, 0);
  k_wtrans<<<4000, 256, 0, stream>>>(wot, out_W, 16000);
  k_gemm2 <<<2000, 256, 0, stream>>>(dech, wot, (float*)d_out, out_b, 16000);
}